// Round 16
// baseline (320.850 us; speedup 1.0000x reference)
//
#include <hip/hip_runtime.h>

typedef unsigned short u16;
typedef __attribute__((ext_vector_type(8))) short bf16x8;
typedef __attribute__((ext_vector_type(4))) float f32x4;
typedef __attribute__((ext_vector_type(4))) u16 u16x4;

#define MFMA16(a, b, c) __builtin_amdgcn_mfma_f32_16x16x32_bf16(a, b, c, 0, 0, 0)

__device__ __forceinline__ u16 f2bf(float f) {
    union { float f; unsigned u; } v; v.f = f;
    unsigned r = (v.u + 0x7FFFu + ((v.u >> 16) & 1u)) >> 16;  // RNE
    return (u16)r;
}

__device__ __forceinline__ void gload_lds16(const void* g, void* l) {
    __builtin_amdgcn_global_load_lds((const __attribute__((address_space(1))) void*)g,
                                     (__attribute__((address_space(3))) void*)l, 16, 0, 0);
}

// ---------- prep: fp32 -> bf16 (optionally scaled) ----------
__global__ __launch_bounds__(256) void cvt_kernel(const float* __restrict__ src,
                                                  u16* __restrict__ dst, int n4, float scale) {
    int i = blockIdx.x * 256 + threadIdx.x;
    if (i >= n4) return;
    f32x4 v = *(const f32x4*)(src + (size_t)i * 4);
    u16x4 o;
#pragma unroll
    for (int j = 0; j < 4; ++j) o[j] = f2bf(v[j] * scale);
    *(u16x4*)(dst + (size_t)i * 4) = o;
}

// ---------- prep: V (8192x512 f32) -> Vt (512x8192 bf16) ----------
__global__ __launch_bounds__(256) void prep_vt(const float* __restrict__ V, u16* __restrict__ Vt) {
    __shared__ float tile[64][65];
    int t = threadIdx.x;
    int n0 = blockIdx.x * 64;
    int d0 = blockIdx.y * 64;
    int tr = t >> 4, tc = t & 15;
#pragma unroll
    for (int p = 0; p < 4; ++p) {
        int n = p * 16 + tr;
        f32x4 v = *(const f32x4*)(V + (size_t)(n0 + n) * 512 + d0 + tc * 4);
#pragma unroll
        for (int j = 0; j < 4; ++j) tile[n][tc * 4 + j] = v[j];
    }
    __syncthreads();
#pragma unroll
    for (int p = 0; p < 4; ++p) {
        int d = p * 16 + tr;
        u16x4 o;
#pragma unroll
        for (int j = 0; j < 4; ++j) o[j] = f2bf(tile[tc * 4 + j][d]);
        *(u16x4*)(Vt + (size_t)(d0 + d) * 8192 + n0 + tc * 4) = o;
    }
}

// ---------- flash attention: desync half-blocks. BM=32, KVBLK=32, key-split 2 ----------
// 256 thr / 4 waves per block, grid 512 -> 2 independent blocks per CU with separate
// barrier domains: one block's S-phase LDS burst overlaps the other's PV/exp/stage.
// Waves: mi(2 x 16 rows) x nj(2 x 16 keys); wave owns dv cols [wid*128,+128) in PV.
// All addressing formulas carried from the R10-verified kernel.
__global__ __launch_bounds__(256) void flash_kernel(
    const u16* __restrict__ Qs, const u16* __restrict__ Kb, const u16* __restrict__ Vt,
    float* __restrict__ Opart, float* __restrict__ lpart) {
    __shared__ __align__(16) u16 lds_k[2][32 * 512];  // 64 KB dbuf, 16B-chunk XOR swizzle
    __shared__ __align__(16) u16 lds_p[2][32 * 32];   // 4 KB P ping-pong, swizzled (4 chunks/row)
    __shared__ float s_l[2][32];

    const int tid = threadIdx.x;
    const int wid = tid >> 6;   // 0..3
    const int lane = tid & 63;
    const int lo = lane & 15;
    const int hi = lane >> 4;
    const int mi = wid >> 1;    // row strip (2 x 16 rows)
    const int nj = wid & 1;     // key strip (2 x 16 keys)

    // same-XCD blocks share a key-split; (bx, bx+256) pair on a CU shares the K/V stream
    const int bx = blockIdx.x;
    const int x = bx & 7;
    const int g = bx >> 3;
    const int ks = x >> 2;
    const int mtile = g * 4 + (x & 3);  // 0..255 (32-row tiles)
    const int key0 = ks * 4096;

    // Q fragments (B-operand of swapped S-MFMA): 16 rows, col=lo, k=kt*32+hi*8+j. 64 VGPR.
    bf16x8 qf[16];
    {
        const u16* qrow = Qs + (size_t)(mtile * 32 + mi * 16 + lo) * 512 + hi * 8;
#pragma unroll
        for (int kt = 0; kt < 16; ++kt) qf[kt] = *(const bf16x8*)(qrow + kt * 32);
    }

    f32x4 o[2][8];  // 32 rows x 128 dv cols (wave owns [wid*128, +128))
#pragma unroll
    for (int a = 0; a < 2; ++a)
#pragma unroll
        for (int b = 0; b < 8; ++b) o[a][b] = (f32x4){0.f, 0.f, 0.f, 0.f};
    float lsum = 0.f;
    bf16x8 vb[8];  // V frags for tile t (8 dv-tiles x 32 keys), consumed by PV at t+1

    // S-read addressing (R10-verified): chunk(kt) = (kt*4+hi) ^ (krow&7), krow = nj*16+lo
    const int cbase = ((hi ^ (lo & 3)) + ((lo >> 2) & 1) * 4) * 8;
    const int rowA = (nj * 16 + lo) * 512;

    // P-write: qrow = mi*16+lo; keys nj*16+hi*4+r -> chunk4 (nj*2+(hi>>1)) ^ (qrow&3)
    const int qrow = mi * 16 + lo;
    const int pw = qrow * 32 + ((((nj << 1) + (hi >> 1)) ^ (qrow & 3)) << 3) + (hi & 1) * 4;

#define STAGE_K(IT, BUF)                                                            \
    {                                                                               \
        const u16* kb_ = Kb + (size_t)(key0 + (IT) * 32) * 512;                     \
        _Pragma("unroll") for (int r8_ = 0; r8_ < 8; ++r8_) {                       \
            int row_ = (wid << 3) + r8_;                                            \
            gload_lds16(kb_ + (size_t)row_ * 512 + ((lane ^ (row_ & 7)) << 3),      \
                        &lds_k[BUF][row_ * 512]);                                   \
        }                                                                           \
    }

// wave's 16 keys x 16 rows over K=512: 16 reads, 16 MFMAs, 2 indep chains
#define S_COMPUTE(BUF, SE, SO)                                                      \
    {                                                                               \
        const u16* pAe = &lds_k[BUF][0] + rowA + cbase;                             \
        const u16* pAo = &lds_k[BUF][0] + rowA + (cbase ^ 32);                      \
        _Pragma("unroll") for (int kt2 = 0; kt2 < 8; ++kt2) {                       \
            bf16x8 ae = *(const bf16x8*)(pAe + kt2 * 64);                           \
            bf16x8 ao = *(const bf16x8*)(pAo + kt2 * 64);                           \
            SE = MFMA16(ae, qf[2 * kt2], SE);                                       \
            SO = MFMA16(ao, qf[2 * kt2 + 1], SO);                                   \
        }                                                                           \
    }

// PV: 2 row-tiles x 8 dv-tiles, k=32 in one MFMA each; pa = P[m][hi*8..+7]
#define PV_STEP(PBUF)                                                               \
    {                                                                               \
        _Pragma("unroll") for (int mt = 0; mt < 2; ++mt) {                          \
            int m = mt * 16 + lo;                                                   \
            bf16x8 pa = *(const bf16x8*)(&lds_p[PBUF][m * 32 + ((hi ^ (m & 3)) << 3)]); \
            _Pragma("unroll") for (int nt = 0; nt < 8; ++nt)                        \
                o[mt][nt] = MFMA16(pa, vb[nt], o[mt][nt]);                          \
        }                                                                           \
    }

#define EXP_PW(S, PBUF)                                                             \
    {                                                                               \
        u16x4 w;                                                                    \
        _Pragma("unroll") for (int r = 0; r < 4; ++r) {                             \
            float p = __expf((S)[r]);                                               \
            lsum += p;                                                              \
            w[r] = f2bf(p);                                                         \
        }                                                                           \
        *(u16x4*)(&lds_p[PBUF][pw]) = w;                                            \
    }

#define VB_LOAD(T)                                                                  \
    {                                                                               \
        _Pragma("unroll") for (int nt = 0; nt < 8; ++nt) {                          \
            vb[nt] = *(const bf16x8*)(Vt + (size_t)(wid * 128 + nt * 16 + lo) * 8192 + \
                                      key0 + (T) * 32 + hi * 8);                    \
        }                                                                           \
    }

    // prologue: K(0) -> buf0
    STAGE_K(0, 0)
    asm volatile("s_waitcnt vmcnt(0)\n\ts_barrier" ::: "memory");

    // iter 0: no PV yet
    {
        STAGE_K(1, 1)
        VB_LOAD(0)
        f32x4 se = {0.f, 0.f, 0.f, 0.f}, so = se;
        __builtin_amdgcn_s_setprio(1);
        S_COMPUTE(0, se, so)
        __builtin_amdgcn_s_setprio(0);
        f32x4 s = se + so;
        EXP_PW(s, 0)
        asm volatile("s_waitcnt vmcnt(0) lgkmcnt(0)\n\ts_barrier" ::: "memory");
    }

    for (int t = 1; t < 128; ++t) {
        const int cur = t & 1;
        if (t < 127) STAGE_K(t + 1, cur ^ 1)
        // PV(t-1): lds_p[cur^1] + vb(t-1), both ready at the barrier
        __builtin_amdgcn_s_setprio(1);
        PV_STEP(cur ^ 1)
        __builtin_amdgcn_s_setprio(0);
        // V(t): overwrite vb after PV consumed it; lands under S(t)
        VB_LOAD(t)
        f32x4 se = {0.f, 0.f, 0.f, 0.f}, so = se;
        __builtin_amdgcn_s_setprio(1);
        S_COMPUTE(cur, se, so)
        __builtin_amdgcn_s_setprio(0);
        f32x4 s = se + so;
        EXP_PW(s, cur)
        asm volatile("s_waitcnt vmcnt(0) lgkmcnt(0)\n\ts_barrier" ::: "memory");
    }

    // epilogue PV for tile 127 (P in lds_p[1], vb holds V(127))
    __builtin_amdgcn_s_setprio(1);
    PV_STEP(1)
    __builtin_amdgcn_s_setprio(0);

    // ---- epilogue: lsum covers wave's 16 keys for qrow; reduce over hi lanes ----
    lsum += __shfl_xor(lsum, 16);
    lsum += __shfl_xor(lsum, 32);
    if (lane < 16) s_l[nj][qrow] = lsum;
    __syncthreads();

    const int lb = mtile * 2 + ks;  // logical partial index
    {
        float* Ob = Opart + (size_t)lb * (32 * 512);
#pragma unroll
        for (int mt = 0; mt < 2; ++mt)
#pragma unroll
            for (int nt = 0; nt < 8; ++nt)
#pragma unroll
                for (int r = 0; r < 4; ++r) {
                    int row = mt * 16 + hi * 4 + r;
                    int col = wid * 128 + nt * 16 + lo;
                    Ob[row * 512 + col] = o[mt][nt][r];
                }
        if (tid < 32) {
            lpart[lb * 32 + tid] = s_l[0][tid] + s_l[1][tid];
        }
    }
}

// ---------- combine the 2 key-split partials: out = (O0+O1)/(l0+l1) ----------
__global__ __launch_bounds__(256) void combine_kernel(const float* __restrict__ Opart,
                                                      const float* __restrict__ lpart,
                                                      float* __restrict__ out) {
    int i = blockIdx.x * 256 + threadIdx.x;  // float4 index; 8192*512/4 = 1048576 total
    int row = i >> 7;
    int c4 = i & 127;
    int mtile = row >> 5, rl = row & 31;
    int b0 = mtile * 2, b1 = b0 + 1;
    float inv = 1.0f / (lpart[b0 * 32 + rl] + lpart[b1 * 32 + rl]);
    f32x4 a = *(const f32x4*)(Opart + (size_t)b0 * 16384 + rl * 512 + c4 * 4);
    f32x4 b = *(const f32x4*)(Opart + (size_t)b1 * 16384 + rl * 512 + c4 * 4);
    f32x4 r = (a + b) * inv;
    *(f32x4*)(out + (size_t)row * 512 + c4 * 4) = r;
}

extern "C" void kernel_launch(void* const* d_in, const int* in_sizes, int n_in,
                              void* d_out, int out_size, void* d_ws, size_t ws_size,
                              hipStream_t stream) {
    const float* Q = (const float*)d_in[0];
    const float* K = (const float*)d_in[1];
    const float* V = (const float*)d_in[2];
    float* out = (float*)d_out;
    char* ws = (char*)d_ws;

    // ws layout (bytes): Qs 8M | Kb 8M | Vt 8M | Opart 32M | lpart 64K
    u16* Qs = (u16*)(ws + 0);
    u16* Kb = (u16*)(ws + 8388608);
    u16* Vt = (u16*)(ws + 16777216);
    float* Op = (float*)(ws + 25165824);
    float* lp = (float*)(ws + 58720256);

    const float scale = 0.08838834764831845f;  // 2 / sqrt(512): softmax(s)^2 renorm == softmax(2s)
    cvt_kernel<<<4096, 256, 0, stream>>>(Q, Qs, 1048576, scale);
    cvt_kernel<<<4096, 256, 0, stream>>>(K, Kb, 1048576, 1.0f);
    prep_vt<<<dim3(128, 8), 256, 0, stream>>>(V, Vt);
    flash_kernel<<<512, 256, 0, stream>>>(Qs, Kb, Vt, Op, lp);
    combine_kernel<<<4096, 256, 0, stream>>>(Op, lp, out);
}

// Round 17
// 215.461 us; speedup vs baseline: 1.4891x; 1.4891x over previous
//
#include <hip/hip_runtime.h>

typedef unsigned short u16;
typedef __attribute__((ext_vector_type(8))) short bf16x8;
typedef __attribute__((ext_vector_type(4))) float f32x4;
typedef __attribute__((ext_vector_type(4))) u16 u16x4;

#define MFMA16(a, b, c) __builtin_amdgcn_mfma_f32_16x16x32_bf16(a, b, c, 0, 0, 0)

__device__ __forceinline__ u16 f2bf(float f) {
    union { float f; unsigned u; } v; v.f = f;
    unsigned r = (v.u + 0x7FFFu + ((v.u >> 16) & 1u)) >> 16;  // RNE
    return (u16)r;
}

__device__ __forceinline__ void gload_lds16(const void* g, void* l) {
    __builtin_amdgcn_global_load_lds((const __attribute__((address_space(1))) void*)g,
                                     (__attribute__((address_space(3))) void*)l, 16, 0, 0);
}

// ---------- prep: fp32 -> bf16 (optionally scaled) ----------
__global__ __launch_bounds__(256) void cvt_kernel(const float* __restrict__ src,
                                                  u16* __restrict__ dst, int n4, float scale) {
    int i = blockIdx.x * 256 + threadIdx.x;
    if (i >= n4) return;
    f32x4 v = *(const f32x4*)(src + (size_t)i * 4);
    u16x4 o;
#pragma unroll
    for (int j = 0; j < 4; ++j) o[j] = f2bf(v[j] * scale);
    *(u16x4*)(dst + (size_t)i * 4) = o;
}

// ---------- prep: V (8192x512 f32) -> Vt (512x8192 bf16) ----------
__global__ __launch_bounds__(256) void prep_vt(const float* __restrict__ V, u16* __restrict__ Vt) {
    __shared__ float tile[64][65];
    int t = threadIdx.x;
    int n0 = blockIdx.x * 64;
    int d0 = blockIdx.y * 64;
    int tr = t >> 4, tc = t & 15;
#pragma unroll
    for (int p = 0; p < 4; ++p) {
        int n = p * 16 + tr;
        f32x4 v = *(const f32x4*)(V + (size_t)(n0 + n) * 512 + d0 + tc * 4);
#pragma unroll
        for (int j = 0; j < 4; ++j) tile[n][tc * 4 + j] = v[j];
    }
    __syncthreads();
#pragma unroll
    for (int p = 0; p < 4; ++p) {
        int d = p * 16 + tr;
        u16x4 o;
#pragma unroll
        for (int j = 0; j < 4; ++j) o[j] = f2bf(tile[tc * 4 + j][d]);
        *(u16x4*)(Vt + (size_t)(d0 + d) * 8192 + n0 + tc * 4) = o;
    }
}

// ---------- flash attention: BM=64, KVBLK=128 (2 sub-tiles), key-split 2 ----------
// Single 128 KB K buffer; one barrier pair per 128 keys: two 64-key sub-tiles (A,B)
// computed back-to-back, stage(t+1) issues after the lgkm-barrier (all S-reads retired)
// and flies under PV_A+PV_B. All fragment/swizzle formulas carried from the R10 kernel;
// sub-tile B = +64 keys = +8 16B-chunks in the [64][128] P tile.
__global__ __launch_bounds__(512) void flash_kernel(
    const u16* __restrict__ Qs, const u16* __restrict__ Kb, const u16* __restrict__ Vt,
    float* __restrict__ Opart, float* __restrict__ lpart) {
    __shared__ __align__(16) u16 lds_k[128 * 512];  // 128 KB single buffer, XOR swizzle
    __shared__ __align__(16) u16 lds_p[64 * 128];   // 16 KB P tile, swizzled per 8-chunk half
    __shared__ float s_l[2][64];

    const int tid = threadIdx.x;
    const int wid = tid >> 6;
    const int lane = tid & 63;
    const int lo = lane & 15;
    const int hi = lane >> 4;
    const int mi = wid >> 1;    // S-phase row strip (4 x 16 rows)
    const int nj = wid & 1;     // S-phase key half (2 x 32 keys per sub-tile)

    // same-XCD blocks share a key-split (L2 reuse of the K/V stream)
    const int bx = blockIdx.x;
    const int x = bx & 7;
    const int g = bx >> 3;
    const int ks = x >> 2;
    const int mtile = g * 4 + (x & 3);
    const int key0 = ks * 4096;

    // Q fragments (B-operand of swapped S-MFMA): 16 rows, col=lo, k=hi*8+j per kt. 64 VGPR.
    bf16x8 qf[16];
    {
        const u16* qrow = Qs + (size_t)(mtile * 64 + mi * 16 + lo) * 512 + hi * 8;
#pragma unroll
        for (int kt = 0; kt < 16; ++kt) qf[kt] = *(const bf16x8*)(qrow + kt * 32);
    }

    f32x4 o[4][4];
#pragma unroll
    for (int a = 0; a < 4; ++a)
#pragma unroll
        for (int b = 0; b < 4; ++b) o[a][b] = (f32x4){0.f, 0.f, 0.f, 0.f};
    float lsum = 0.f;
    bf16x8 vbA[4][2], vbB[4][2];

    // S-read addressing (verified): chunk(kt) = (kt*4+hi) ^ (krow&7); krow = nj*32+lo (+64 for B)
    const int cbase = ((hi ^ (lo & 3)) + ((lo >> 2) & 1) * 4) * 8;
    const int rowA_A = (nj * 32 + lo) * 512;
    const int rowA_B = rowA_A + 64 * 512;  // +64 keys; (64+..)&7 pattern identical

    // P-write (verified, row stride now 128): row = mi*16+lo; sub-A chunks 0-7, sub-B +8 (+64 elems)
    const int qrow = mi * 16 + lo;
    const int chA0 = ((nj * 4 + (hi >> 1)) ^ (qrow & 7));
    const int chA1 = ((nj * 4 + 2 + (hi >> 1)) ^ (qrow & 7));
    const int pwA0 = qrow * 128 + (chA0 << 3) + (hi & 1) * 4;
    const int pwA1 = qrow * 128 + (chA1 << 3) + (hi & 1) * 4;
    const int pwB0 = pwA0 + 64;
    const int pwB1 = pwA1 + 64;

#define STAGE_K(IT)                                                                 \
    {                                                                               \
        const u16* kb_ = Kb + (size_t)(key0 + (IT) * 128) * 512;                    \
        _Pragma("unroll") for (int r_ = 0; r_ < 16; ++r_) {                         \
            int row_ = (wid << 4) + r_;                                             \
            gload_lds16(kb_ + (size_t)row_ * 512 + ((lane ^ (row_ & 7)) << 3),      \
                        &lds_k[row_ * 512]);                                        \
        }                                                                           \
    }

// 4 independent MFMA chains (depth 8 each); ROWBASE selects sub-tile
#define S_COMPUTE(ROWBASE, S0A, S0B, S1A, S1B)                                      \
    {                                                                               \
        const u16* pAe = &lds_k[0] + (ROWBASE) + cbase;                             \
        const u16* pAo = &lds_k[0] + (ROWBASE) + (cbase ^ 32);                      \
        const u16* pBe = pAe + 16 * 512;                                            \
        const u16* pBo = pAo + 16 * 512;                                            \
        _Pragma("unroll") for (int kt2 = 0; kt2 < 8; ++kt2) {                       \
            bf16x8 ae = *(const bf16x8*)(pAe + kt2 * 64);                           \
            bf16x8 be = *(const bf16x8*)(pBe + kt2 * 64);                           \
            bf16x8 ao = *(const bf16x8*)(pAo + kt2 * 64);                           \
            bf16x8 bo = *(const bf16x8*)(pBo + kt2 * 64);                           \
            S0A = MFMA16(ae, qf[2 * kt2], S0A);                                     \
            S1A = MFMA16(be, qf[2 * kt2], S1A);                                     \
            S0B = MFMA16(ao, qf[2 * kt2 + 1], S0B);                                 \
            S1B = MFMA16(bo, qf[2 * kt2 + 1], S1B);                                 \
        }                                                                           \
    }

// PV sub-tile: CH_OFF = 0 (keys 0-63) or 8 (keys 64-127); V frags in VB
#define PV_STEP(CH_OFF, VB)                                                         \
    {                                                                               \
        _Pragma("unroll") for (int mt = 0; mt < 4; ++mt) {                          \
            int m = mt * 16 + lo;                                                   \
            int c0 = (CH_OFF) + (hi ^ (m & 7));                                     \
            int c1 = (CH_OFF) + ((4 + hi) ^ (m & 7));                               \
            bf16x8 pa0 = *(const bf16x8*)(&lds_p[m * 128 + c0 * 8]);                \
            bf16x8 pa1 = *(const bf16x8*)(&lds_p[m * 128 + c1 * 8]);                \
            _Pragma("unroll") for (int nt = 0; nt < 4; ++nt) {                      \
                f32x4 c_ = o[mt][nt];                                               \
                c_ = MFMA16(pa0, VB[nt][0], c_);                                    \
                c_ = MFMA16(pa1, VB[nt][1], c_);                                    \
                o[mt][nt] = c_;                                                     \
            }                                                                       \
        }                                                                           \
    }

#define EXP_PW(S0, S1, PW0, PW1)                                                    \
    {                                                                               \
        u16x4 w0, w1;                                                               \
        _Pragma("unroll") for (int r = 0; r < 4; ++r) {                             \
            float p0 = __expf((S0)[r]);                                             \
            float p1 = __expf((S1)[r]);                                             \
            lsum += p0 + p1;                                                        \
            w0[r] = f2bf(p0);                                                       \
            w1[r] = f2bf(p1);                                                       \
        }                                                                           \
        *(u16x4*)(&lds_p[PW0]) = w0;                                                \
        *(u16x4*)(&lds_p[PW1]) = w1;                                                \
    }

#define VB_LOAD(T, KOFF, VB)                                                        \
    {                                                                               \
        _Pragma("unroll") for (int nt = 0; nt < 4; ++nt) {                          \
            const u16* vrow = Vt + (size_t)(wid * 64 + nt * 16 + lo) * 8192 +       \
                              key0 + (T) * 128 + (KOFF) + hi * 8;                   \
            VB[nt][0] = *(const bf16x8*)(vrow);                                     \
            VB[nt][1] = *(const bf16x8*)(vrow + 32);                                \
        }                                                                           \
    }

    // prologue: K(0) -> buffer
    STAGE_K(0)
    asm volatile("s_waitcnt vmcnt(0)\n\ts_barrier" ::: "memory");

    for (int t = 0; t < 32; ++t) {
        // ---- sub-tile A: keys [t*128, +64) ----
        VB_LOAD(t, 0, vbA)
        f32x4 a0a = {0.f, 0.f, 0.f, 0.f}, a0b = a0a, a1a = a0a, a1b = a0a;
        __builtin_amdgcn_s_setprio(1);
        S_COMPUTE(rowA_A, a0a, a0b, a1a, a1b)
        __builtin_amdgcn_s_setprio(0);
        f32x4 sA0 = a0a + a0b, sA1 = a1a + a1b;
        EXP_PW(sA0, sA1, pwA0, pwA1)

        // ---- sub-tile B: keys [t*128+64, +64) ----
        VB_LOAD(t, 64, vbB)
        f32x4 b0a = {0.f, 0.f, 0.f, 0.f}, b0b = b0a, b1a = b0a, b1b = b0a;
        __builtin_amdgcn_s_setprio(1);
        S_COMPUTE(rowA_B, b0a, b0b, b1a, b1b)
        __builtin_amdgcn_s_setprio(0);
        f32x4 sB0 = b0a + b0b, sB1 = b1a + b1b;
        EXP_PW(sB0, sB1, pwB0, pwB1)

        // ---- P visible AND all lds_k reads retired -> safe to overwrite K buffer ----
        asm volatile("s_waitcnt lgkmcnt(0)\n\ts_barrier" ::: "memory");

        if (t < 31) STAGE_K(t + 1)  // flies under PV_A + PV_B

        __builtin_amdgcn_s_setprio(1);
        PV_STEP(0, vbA)
        PV_STEP(8, vbB)
        __builtin_amdgcn_s_setprio(0);

        // end barrier: stage(t+1) drained; PV's lds_p reads retired before next P-write
        if (t < 31) asm volatile("s_waitcnt vmcnt(0) lgkmcnt(0)\n\ts_barrier" ::: "memory");
    }

    // ---- epilogue: lsum covers wave's 32 keys (x2 sub-tiles) for qrow; reduce over hi ----
    lsum += __shfl_xor(lsum, 16);
    lsum += __shfl_xor(lsum, 32);
    if (lane < 16) s_l[nj][qrow] = lsum;
    __syncthreads();

    const int lb = mtile * 2 + ks;  // logical partial index
    {
        float* Ob = Opart + (size_t)lb * (64 * 512);
#pragma unroll
        for (int mt = 0; mt < 4; ++mt)
#pragma unroll
            for (int nt = 0; nt < 4; ++nt)
#pragma unroll
                for (int r = 0; r < 4; ++r) {
                    int row = mt * 16 + hi * 4 + r;
                    int col = wid * 64 + nt * 16 + lo;
                    Ob[row * 512 + col] = o[mt][nt][r];
                }
        if (tid < 64) {
            lpart[lb * 64 + tid] = s_l[0][tid] + s_l[1][tid];
        }
    }
}

// ---------- combine the 2 key-split partials: out = (O0+O1)/(l0+l1) ----------
__global__ __launch_bounds__(256) void combine_kernel(const float* __restrict__ Opart,
                                                      const float* __restrict__ lpart,
                                                      float* __restrict__ out) {
    int i = blockIdx.x * 256 + threadIdx.x;  // float4 index; 8192*512/4 = 1048576 total
    int row = i >> 7;
    int c4 = i & 127;
    int mtile = row >> 6, rl = row & 63;
    int b0 = mtile * 2, b1 = b0 + 1;
    float inv = 1.0f / (lpart[b0 * 64 + rl] + lpart[b1 * 64 + rl]);
    f32x4 a = *(const f32x4*)(Opart + (size_t)b0 * 32768 + rl * 512 + c4 * 4);
    f32x4 b = *(const f32x4*)(Opart + (size_t)b1 * 32768 + rl * 512 + c4 * 4);
    f32x4 r = (a + b) * inv;
    *(f32x4*)(out + (size_t)row * 512 + c4 * 4) = r;
}

extern "C" void kernel_launch(void* const* d_in, const int* in_sizes, int n_in,
                              void* d_out, int out_size, void* d_ws, size_t ws_size,
                              hipStream_t stream) {
    const float* Q = (const float*)d_in[0];
    const float* K = (const float*)d_in[1];
    const float* V = (const float*)d_in[2];
    float* out = (float*)d_out;
    char* ws = (char*)d_ws;

    // ws layout (bytes): Qs 8M | Kb 8M | Vt 8M | Opart 32M | lpart 64K
    u16* Qs = (u16*)(ws + 0);
    u16* Kb = (u16*)(ws + 8388608);
    u16* Vt = (u16*)(ws + 16777216);
    float* Op = (float*)(ws + 25165824);
    float* lp = (float*)(ws + 58720256);

    const float scale = 0.08838834764831845f;  // 2 / sqrt(512): softmax(s)^2 renorm == softmax(2s)
    cvt_kernel<<<4096, 256, 0, stream>>>(Q, Qs, 1048576, scale);
    cvt_kernel<<<4096, 256, 0, stream>>>(K, Kb, 1048576, 1.0f);
    prep_vt<<<dim3(128, 8), 256, 0, stream>>>(V, Vt);
    flash_kernel<<<256, 512, 0, stream>>>(Qs, Kb, Vt, Op, lp);
    combine_kernel<<<4096, 256, 0, stream>>>(Op, lp, out);
}